// Round 5
// baseline (540.490 us; speedup 1.0000x reference)
//
#include <hip/hip_runtime.h>
#include <hip/hip_bf16.h>
#include <math.h>

#define HIDDEN 2048
#define NHEADS 16
#define NKV 4
#define HD 128
#define SEQ 2048
#define BATCH 2
#define MTOT (BATCH*SEQ)     // 4096
#define NQ (NHEADS*HD)       // 2048
#define NKVD (NKV*HD)        // 512
#define NQKV (NQ + 2*NKVD)   // 3072

typedef __attribute__((ext_vector_type(8))) short short8;
typedef __attribute__((ext_vector_type(4))) float float4v;

#if __has_builtin(__builtin_amdgcn_exp2f)
#define EXP2F __builtin_amdgcn_exp2f
#else
#define EXP2F exp2f
#endif
#define C1 0.1275174f   // (1/sqrt(128)) * log2(e)

static __device__ __forceinline__ unsigned short f2bf(float f) {
  union { float f; unsigned int u; } v; v.f = f;
  unsigned int r = v.u + 0x7FFF + ((v.u >> 16) & 1);
  return (unsigned short)(r >> 16);
}
static __device__ __forceinline__ float bf2f(unsigned short h) {
  union { unsigned int u; float f; } v; v.u = ((unsigned int)h) << 16;
  return v.f;
}

// async global->LDS, 16B per lane; LDS dest = uniform base + lane*16
static __device__ __forceinline__ void async16(const unsigned short* g, unsigned short* l) {
  __builtin_amdgcn_global_load_lds(
      (const __attribute__((address_space(1))) unsigned int*)g,
      (__attribute__((address_space(3))) unsigned int*)l, 16, 0, 0);
}

// ---------------- cast fp32 -> bf16 (vectorized x4) ----------------
__global__ void cast_f32_bf16(const float* __restrict__ in,
                              unsigned short* __restrict__ out, int n) {
  int i = (blockIdx.x * blockDim.x + threadIdx.x) * 4;
  if (i < n) {
    float4 v = *(const float4*)(in + i);
    ushort4 o;
    o.x = f2bf(v.x); o.y = f2bf(v.y); o.z = f2bf(v.z); o.w = f2bf(v.w);
    *(ushort4*)(out + i) = o;
  }
}

// ---------------- transpose + cast: W[K][N] fp32 -> Wt[N][K] bf16 ----------------
__global__ void transpose_cast(const float* __restrict__ W,
                               unsigned short* __restrict__ Wt, int K, int N) {
  __shared__ float tile[32][33];
  int tn = blockIdx.x * 32;
  int tk = blockIdx.y * 32;
  int tx = threadIdx.x & 31;
  int ty = threadIdx.x >> 5;  // 0..7
  #pragma unroll
  for (int i = 0; i < 4; i++) {
    int k = tk + ty + i * 8;
    tile[ty + i * 8][tx] = W[(size_t)k * N + tn + tx];
  }
  __syncthreads();
  #pragma unroll
  for (int i = 0; i < 4; i++) {
    int n = tn + ty + i * 8;
    Wt[(size_t)n * K + tk + tx] = f2bf(tile[tx][ty + i * 8]);
  }
}

// ---------------- RoPE in place on [B][S][nheads][128] bf16 ----------------
__global__ void rope_kernel(unsigned short* __restrict__ Qb, int nheads) {
  int idx = blockIdx.x * blockDim.x + threadIdx.x;
  int d = idx & 63;
  int hr = idx >> 6;                 // (b*SEQ + s)*nheads + h
  int spos = (hr / nheads) % SEQ;
  size_t base = (size_t)hr * HD;
  float inv = exp2f((float)d * -0.2076205059304601f);  // 10000^(-d/64)
  float ang = (float)spos * inv;
  float sn, cs;
  sincosf(ang, &sn, &cs);
  float q1 = bf2f(Qb[base + d]);
  float q2 = bf2f(Qb[base + d + 64]);
  Qb[base + d]      = f2bf(q1 * cs - q2 * sn);
  Qb[base + d + 64] = f2bf(q2 * cs + q1 * sn);
}

// ================= fused QKV GEMM: xb[4096][2048] x Wqkvt[3072][2048]^T ================
// dbuf LDS, swizzled staging/reads (2-way banks). V-blocks (bx>=20) use
// operand-swapped MFMA so V^T stores are row-coalesced.
__global__ __launch_bounds__(256) void gemm_qkv(
    const unsigned short* __restrict__ A,
    const unsigned short* __restrict__ Bt,
    unsigned short* __restrict__ Qb,
    unsigned short* __restrict__ Kb,
    unsigned short* __restrict__ Vt) {
  __shared__ unsigned short As0[128 * 32], Bs0[128 * 32];
  __shared__ unsigned short As1[128 * 32], Bs1[128 * 32];
  const int K = HIDDEN;
  int bm = blockIdx.y * 128, bn = blockIdx.x * 128;
  int tid = threadIdx.x, w = tid >> 6, lane = tid & 63;
  int wm = (w >> 1) * 64, wn = (w & 1) * 64;
  int m16 = lane & 15, quad = lane >> 4;
  int lrow = lane >> 2, lch = lane & 3;
  int lchs = lch ^ ((lrow >> 1) & 3);          // swizzled staging piece
  int qx = quad ^ ((m16 >> 1) & 3);            // swizzled read piece
  const unsigned short* Ag = A + (size_t)(bm + w * 32 + lrow) * K + lchs * 8;
  const unsigned short* Bg = Bt + (size_t)(bn + w * 32 + lrow) * K + lchs * 8;
  int woff = w * 1024;

  float4v acc[4][4];
  #pragma unroll
  for (int i = 0; i < 4; i++)
    #pragma unroll
    for (int j = 0; j < 4; j++) acc[i][j] = (float4v)0.0f;

  auto stage = [&](int k0, unsigned short* Asl, unsigned short* Bsl) {
    #pragma unroll
    for (int i = 0; i < 2; i++) {
      async16(Ag + (size_t)i * 16 * K + k0, Asl + woff + i * 512);
      async16(Bg + (size_t)i * 16 * K + k0, Bsl + woff + i * 512);
    }
  };
  auto computeN = [&](const unsigned short* As, const unsigned short* Bs) {
    short8 af[4], bfr[4];
    #pragma unroll
    for (int i = 0; i < 4; i++)
      af[i] = *(const short8*)(&As[(wm + i * 16 + m16) * 32 + qx * 8]);
    #pragma unroll
    for (int j = 0; j < 4; j++)
      bfr[j] = *(const short8*)(&Bs[(wn + j * 16 + m16) * 32 + qx * 8]);
    #pragma unroll
    for (int i = 0; i < 4; i++)
      #pragma unroll
      for (int j = 0; j < 4; j++)
        acc[i][j] = __builtin_amdgcn_mfma_f32_16x16x32_bf16(af[i], bfr[j], acc[i][j], 0, 0, 0);
  };
  auto computeS = [&](const unsigned short* As, const unsigned short* Bs) {
    short8 af[4], bfr[4];
    #pragma unroll
    for (int i = 0; i < 4; i++)
      af[i] = *(const short8*)(&As[(wm + i * 16 + m16) * 32 + qx * 8]);
    #pragma unroll
    for (int j = 0; j < 4; j++)
      bfr[j] = *(const short8*)(&Bs[(wn + j * 16 + m16) * 32 + qx * 8]);
    #pragma unroll
    for (int i = 0; i < 4; i++)
      #pragma unroll
      for (int j = 0; j < 4; j++)
        acc[i][j] = __builtin_amdgcn_mfma_f32_16x16x32_bf16(bfr[j], af[i], acc[i][j], 0, 0, 0);
  };

  bool isV = (blockIdx.x >= 20);
  stage(0, As0, Bs0);
  if (!isV) {
    for (int k0 = 0; k0 < K; k0 += 64) {
      __syncthreads();
      if (k0 + 32 < K) stage(k0 + 32, As1, Bs1);
      computeN(As0, Bs0);
      __syncthreads();
      if (k0 + 64 < K) stage(k0 + 64, As0, Bs0);
      computeN(As1, Bs1);
    }
  } else {
    for (int k0 = 0; k0 < K; k0 += 64) {
      __syncthreads();
      if (k0 + 32 < K) stage(k0 + 32, As1, Bs1);
      computeS(As0, Bs0);
      __syncthreads();
      if (k0 + 64 < K) stage(k0 + 64, As0, Bs0);
      computeS(As1, Bs1);
    }
  }

  if (blockIdx.x < 16) {
    #pragma unroll
    for (int i = 0; i < 4; i++)
      #pragma unroll
      for (int j = 0; j < 4; j++)
        #pragma unroll
        for (int r = 0; r < 4; r++) {
          int row = bm + wm + i * 16 + quad * 4 + r;
          int col = bn + wn + j * 16 + m16;
          Qb[(size_t)row * NQ + col] = f2bf(acc[i][j][r]);
        }
  } else if (!isV) {
    #pragma unroll
    for (int i = 0; i < 4; i++)
      #pragma unroll
      for (int j = 0; j < 4; j++)
        #pragma unroll
        for (int r = 0; r < 4; r++) {
          int row = bm + wm + i * 16 + quad * 4 + r;
          int col = bn - 2048 + wn + j * 16 + m16;
          Kb[(size_t)row * NKVD + col] = f2bf(acc[i][j][r]);
        }
  } else {
    // swapped layout: row(quad*4+r) = f-tile j, col(m16) = m-tile i
    #pragma unroll
    for (int i = 0; i < 4; i++)
      #pragma unroll
      for (int j = 0; j < 4; j++)
        #pragma unroll
        for (int r = 0; r < 4; r++) {
          int f = bn - 2560 + wn + j * 16 + quad * 4 + r;
          int m = bm + wm + i * 16 + m16;
          Vt[(size_t)f * MTOT + m] = f2bf(acc[i][j][r]);
        }
  }
}

// ================= O-projection GEMM (dbuf + swizzle, fp32 out) =================
__global__ __launch_bounds__(256) void gemm_o(
    const unsigned short* __restrict__ A,
    const unsigned short* __restrict__ Bt,
    float* __restrict__ C, int M, int N, int K) {
  __shared__ unsigned short As0[128 * 32], Bs0[128 * 32];
  __shared__ unsigned short As1[128 * 32], Bs1[128 * 32];
  int bm = blockIdx.y * 128, bn = blockIdx.x * 128;
  int tid = threadIdx.x, w = tid >> 6, lane = tid & 63;
  int wm = (w >> 1) * 64, wn = (w & 1) * 64;
  int m16 = lane & 15, quad = lane >> 4;
  int lrow = lane >> 2, lch = lane & 3;
  int lchs = lch ^ ((lrow >> 1) & 3);
  int qx = quad ^ ((m16 >> 1) & 3);
  const unsigned short* Ag = A + (size_t)(bm + w * 32 + lrow) * K + lchs * 8;
  const unsigned short* Bg = Bt + (size_t)(bn + w * 32 + lrow) * K + lchs * 8;
  int woff = w * 1024;

  float4v acc[4][4];
  #pragma unroll
  for (int i = 0; i < 4; i++)
    #pragma unroll
    for (int j = 0; j < 4; j++) acc[i][j] = (float4v)0.0f;

  auto stage = [&](int k0, unsigned short* Asl, unsigned short* Bsl) {
    #pragma unroll
    for (int i = 0; i < 2; i++) {
      async16(Ag + (size_t)i * 16 * K + k0, Asl + woff + i * 512);
      async16(Bg + (size_t)i * 16 * K + k0, Bsl + woff + i * 512);
    }
  };
  auto compute = [&](const unsigned short* As, const unsigned short* Bs) {
    short8 af[4], bfr[4];
    #pragma unroll
    for (int i = 0; i < 4; i++)
      af[i] = *(const short8*)(&As[(wm + i * 16 + m16) * 32 + qx * 8]);
    #pragma unroll
    for (int j = 0; j < 4; j++)
      bfr[j] = *(const short8*)(&Bs[(wn + j * 16 + m16) * 32 + qx * 8]);
    #pragma unroll
    for (int i = 0; i < 4; i++)
      #pragma unroll
      for (int j = 0; j < 4; j++)
        acc[i][j] = __builtin_amdgcn_mfma_f32_16x16x32_bf16(af[i], bfr[j], acc[i][j], 0, 0, 0);
  };

  stage(0, As0, Bs0);
  for (int k0 = 0; k0 < K; k0 += 64) {
    __syncthreads();
    if (k0 + 32 < K) stage(k0 + 32, As1, Bs1);
    compute(As0, Bs0);
    __syncthreads();
    if (k0 + 64 < K) stage(k0 + 64, As0, Bs0);
    compute(As1, Bs1);
  }

  #pragma unroll
  for (int i = 0; i < 4; i++)
    #pragma unroll
    for (int j = 0; j < 4; j++)
      #pragma unroll
      for (int r = 0; r < 4; r++) {
        int row = bm + wm + i * 16 + quad * 4 + r;
        int col = bn + wn + j * 16 + m16;
        C[(size_t)row * N + col] = acc[i][j][r];
      }
}

// ---------------- Flash attention: 48 KB LDS, P overlays dead K buffer ----------------
// Per iter: TOP barrier -> issue V(kt) -> S from CUR -> issue K(kt+1)->NXT ->
// softmax (P packed in regs) -> MID barrier (drains V+K; orders S-reads before
// P-writes) -> P-write into CUR (wave-private rows) -> PV -> loop.
#define FLASH_TILE(CUR, NXT)                                                  \
  {                                                                           \
    const int ktb = kt * 64;                                                  \
    __syncthreads(); /* TOP */                                                \
    {                                                                         \
      const unsigned short* Vg = Vt + vgrow * (size_t)MTOT                    \
                                    + (size_t)b * SEQ + ktb + kcv * 32 + vlch * 8; \
      unsigned short* Vl = Vs + kcv * 4096 + ipv * 512;                       \
      _Pragma("unroll")                                                       \
      for (int i = 0; i < 4; i++) async16(Vg + (size_t)i * 16 * MTOT, Vl + i * 512); \
    }                                                                         \
    const bool act = (ktb <= wqmax);                                          \
    float4v sacc[2][4];                                                       \
    if (act) {                                                                \
      _Pragma("unroll") for (int qs = 0; qs < 2; qs++)                        \
        _Pragma("unroll") for (int s4 = 0; s4 < 4; s4++) sacc[qs][s4] = (float4v)0.0f; \
      _Pragma("unroll")                                                       \
      for (int s4 = 0; s4 < 4; s4++)                                          \
        _Pragma("unroll")                                                     \
        for (int c = 0; c < 4; c++) {                                         \
          short8 kf = *(const short8*)(&CUR[c * 2048 + (s4 * 16 + m16) * 32 + qx * 8]); \
          sacc[0][s4] = __builtin_amdgcn_mfma_f32_16x16x32_bf16(kf, qf[0][c], sacc[0][s4], 0, 0, 0); \
          sacc[1][s4] = __builtin_amdgcn_mfma_f32_16x16x32_bf16(kf, qf[1][c], sacc[1][s4], 0, 0, 0); \
        }                                                                     \
    }                                                                         \
    if (kt < H) {                                                             \
      const unsigned short* Kg = Kp + (((size_t)b * SEQ + (kt + 1) * 64 + lrow) * NKV + kvh) * HD + w * 32 + vlch * 8; \
      unsigned short* Kl = NXT + w * 2048;                                    \
      _Pragma("unroll")                                                       \
      for (int i = 0; i < 4; i++) async16(Kg + (size_t)i * 16 * NKV * HD, Kl + i * 512); \
    }                                                                         \
    unsigned int pu[2][4][2];                                                 \
    if (act) {                                                                \
      _Pragma("unroll")                                                       \
      for (int qs = 0; qs < 2; qs++) {                                        \
        const int qabs = wqbase + qs * 16 + m16;                              \
        const bool diag = (ktb + 63) > (wqbase + qs * 16);                    \
        float sv[4][4]; float mloc = -1e30f;                                  \
        if (diag) {                                                           \
          _Pragma("unroll") for (int s4 = 0; s4 < 4; s4++)                    \
            _Pragma("unroll") for (int r = 0; r < 4; r++) {                   \
              int kabs = ktb + s4 * 16 + quad * 4 + r;                        \
              float t = sacc[qs][s4][r];                                      \
              sv[s4][r] = (kabs > qabs) ? -1e30f : t;                         \
              mloc = fmaxf(mloc, sv[s4][r]); }                                \
        } else {                                                              \
          _Pragma("unroll") for (int s4 = 0; s4 < 4; s4++)                    \
            _Pragma("unroll") for (int r = 0; r < 4; r++) {                   \
              sv[s4][r] = sacc[qs][s4][r]; mloc = fmaxf(mloc, sv[s4][r]); }   \
        }                                                                     \
        mloc *= C1;                                                           \
        mloc = fmaxf(mloc, __shfl_xor(mloc, 16, 64));                         \
        mloc = fmaxf(mloc, __shfl_xor(mloc, 32, 64));                         \
        const float mnewS = fmaxf(miS[qs], mloc);                             \
        float rs = 0.0f;                                                      \
        _Pragma("unroll") for (int s4 = 0; s4 < 4; s4++) {                    \
          float p0 = EXP2F(__builtin_fmaf(sv[s4][0], C1, -mnewS));            \
          float p1 = EXP2F(__builtin_fmaf(sv[s4][1], C1, -mnewS));            \
          float p2 = EXP2F(__builtin_fmaf(sv[s4][2], C1, -mnewS));            \
          float p3 = EXP2F(__builtin_fmaf(sv[s4][3], C1, -mnewS));            \
          rs += p0 + p1 + p2 + p3;                                            \
          pu[qs][s4][0] = (__float_as_uint(p1) & 0xffff0000u) | (__float_as_uint(p0) >> 16); \
          pu[qs][s4][1] = (__float_as_uint(p3) & 0xffff0000u) | (__float_as_uint(p2) >> 16); \
        }                                                                     \
        rs += __shfl_xor(rs, 16, 64);                                         \
        rs += __shfl_xor(rs, 32, 64);                                         \
        const float alpha = EXP2F(miS[qs] - mnewS);                           \
        li[qs] = li[qs] * alpha + rs; miS[qs] = mnewS;                        \
        _Pragma("unroll") for (int ds = 0; ds < 8; ds++) oacc[ds][qs] *= alpha; \
      }                                                                       \
    }                                                                         \
    __syncthreads(); /* MID: drains V+K; all S-reads done before P overlay */ \
    if (act) {                                                                \
      unsigned int* Pp = (unsigned int*)CUR;                                  \
      _Pragma("unroll")                                                       \
      for (int qs = 0; qs < 2; qs++) {                                        \
        const int prow = qlocal0 + qs * 16 + m16;                             \
        const int psw = prow * 32; const int rx = prow & 7;                   \
        _Pragma("unroll") for (int s4 = 0; s4 < 4; s4++) {                    \
          uint2 u; u.x = pu[qs][s4][0]; u.y = pu[qs][s4][1];                  \
          int chunkW = s4 * 2 + (quad >> 1);                                  \
          *(uint2*)(&Pp[psw + ((chunkW ^ rx) << 2) + (quad & 1) * 2]) = u;    \
        }                                                                     \
      }                                                                       \
      const int r0 = qlocal0 + m16, r1 = qlocal0 + 16 + m16;                  \
      _Pragma("unroll")                                                       \
      for (int kc = 0; kc < 2; kc++) {                                        \
        short8 pf0 = *(const short8*)(&Pp[r0 * 32 + (((kc * 4 + quad) ^ (r0 & 7)) << 2)]); \
        short8 pf1 = *(const short8*)(&Pp[r1 * 32 + (((kc * 4 + quad) ^ (r1 & 7)) << 2)]); \
        _Pragma("unroll")                                                     \
        for (int ds = 0; ds < 8; ds++) {                                      \
          short8 vf = *(const short8*)(&Vs[kc * 4096 + (ds * 16 + m16) * 32 + qx * 8]); \
          oacc[ds][0] = __builtin_amdgcn_mfma_f32_16x16x32_bf16(vf, pf0, oacc[ds][0], 0, 0, 0); \
          oacc[ds][1] = __builtin_amdgcn_mfma_f32_16x16x32_bf16(vf, pf1, oacc[ds][1], 0, 0, 0); \
        }                                                                     \
      }                                                                       \
    }                                                                         \
  }

__global__ __launch_bounds__(256, 3) void flash_attn(
    const unsigned short* __restrict__ Q,
    const unsigned short* __restrict__ Kp,
    const unsigned short* __restrict__ Vt,
    unsigned short* __restrict__ O) {
  __shared__ unsigned short Ks0[4 * 64 * 32];  // 16 KB [dchunk][key][32d]; P overlay after S
  __shared__ unsigned short Ks1[4 * 64 * 32];  // 16 KB
  __shared__ unsigned short Vs[2 * 128 * 32];  // 16 KB [kchunk][d][32seq]

  int bx = blockIdx.x;            // 0..15
  int h  = blockIdx.y;
  int b  = blockIdx.z;
  int kvh = h >> 2;
  int H = 31 - bx, L = bx;
  int tid = threadIdx.x;
  int w = tid >> 6, lane = tid & 63;
  int m16 = lane & 15, quad = lane >> 4;
  int lrow = lane >> 2, lch = lane & 3;
  const int vlch = lch ^ ((lrow >> 1) & 3);   // swizzled staging piece
  const int qx = quad ^ ((m16 >> 1) & 3);     // swizzled read piece

  int wqbase = (w < 2) ? (H * 64 + w * 32) : (L * 64 + (w - 2) * 32);
  int wqmax = wqbase + 31;
  int qlocal0 = w * 32;
  const int kcv = w >> 1, ipv = (w & 1) * 4;
  const size_t vgrow = (size_t)kvh * HD + ipv * 16 + lrow;

  short8 qf[2][4];
  #pragma unroll
  for (int qs = 0; qs < 2; qs++) {
    size_t qbase = (((size_t)b * SEQ + wqbase + qs * 16 + m16) * NHEADS + h) * HD;
    #pragma unroll
    for (int c = 0; c < 4; c++)
      qf[qs][c] = *(const short8*)(Q + qbase + c * 32 + quad * 8);
  }

  float4v oacc[8][2];
  #pragma unroll
  for (int ds = 0; ds < 8; ds++) { oacc[ds][0] = (float4v)0.0f; oacc[ds][1] = (float4v)0.0f; }
  float miS[2] = {-1e30f, -1e30f}, li[2] = {0.0f, 0.0f};

  // prologue: stage K(0) into Ks0 (drained at first TOP barrier)
  {
    const unsigned short* Kg = Kp + (((size_t)b * SEQ + lrow) * NKV + kvh) * HD + w * 32 + vlch * 8;
    unsigned short* Kl = Ks0 + w * 2048;
    #pragma unroll
    for (int i = 0; i < 4; i++) async16(Kg + (size_t)i * 16 * NKV * HD, Kl + i * 512);
  }

  int kt = 0;
  for (;;) {
    FLASH_TILE(Ks0, Ks1)
    if (++kt > H) break;
    FLASH_TILE(Ks1, Ks0)
    if (++kt > H) break;
  }

  #pragma unroll
  for (int qs = 0; qs < 2; qs++) {
    float inv = 1.0f / li[qs];
    int qabs = wqbase + qs * 16 + m16;
    size_t obase = (((size_t)b * SEQ + qabs) * NHEADS + h) * HD + quad * 4;
    #pragma unroll
    for (int ds = 0; ds < 8; ds++) {
      float v0 = oacc[ds][qs][0] * inv;
      float v1 = oacc[ds][qs][1] * inv;
      float v2 = oacc[ds][qs][2] * inv;
      float v3 = oacc[ds][qs][3] * inv;
      uint2 u;
      u.x = ((unsigned)f2bf(v1) << 16) | f2bf(v0);
      u.y = ((unsigned)f2bf(v3) << 16) | f2bf(v2);
      *(uint2*)(O + obase + ds * 16) = u;
    }
  }
}

extern "C" void kernel_launch(void* const* d_in, const int* in_sizes, int n_in,
                              void* d_out, int out_size, void* d_ws, size_t ws_size,
                              hipStream_t stream) {
  const float* x  = (const float*)d_in[0];
  const float* Wq = (const float*)d_in[1];
  const float* Wk = (const float*)d_in[2];
  const float* Wv = (const float*)d_in[3];
  const float* Wo = (const float*)d_in[4];
  float* out = (float*)d_out;

  unsigned short* ws = (unsigned short*)d_ws;
  unsigned short* xb  = ws;                              // [4096][2048]
  unsigned short* Wqt = xb  + (size_t)MTOT * HIDDEN;     // [2048][2048] (Wqt/Wkt/Wvt contiguous = Wqkvt)
  unsigned short* Wkt = Wqt + (size_t)NQ * HIDDEN;       // [512][2048]
  unsigned short* Wvt = Wkt + (size_t)NKVD * HIDDEN;     // [512][2048]
  unsigned short* Wot = Wvt + (size_t)NKVD * HIDDEN;     // [2048][2048]
  unsigned short* Qb  = Wot + (size_t)NQ * HIDDEN;       // [4096][2048]
  unsigned short* Kb  = Qb  + (size_t)MTOT * NQ;         // [4096][512]
  unsigned short* Vtb = Kb  + (size_t)MTOT * NKVD;       // [512][4096]  (V^T)
  unsigned short* Ab  = Vtb + (size_t)MTOT * NKVD;       // [4096][2048]

  cast_f32_bf16<<<(MTOT * HIDDEN / 4 + 255) / 256, 256, 0, stream>>>(x, xb, MTOT * HIDDEN);
  transpose_cast<<<dim3(NQ / 32, HIDDEN / 32), 256, 0, stream>>>(Wq, Wqt, HIDDEN, NQ);
  transpose_cast<<<dim3(NKVD / 32, HIDDEN / 32), 256, 0, stream>>>(Wk, Wkt, HIDDEN, NKVD);
  transpose_cast<<<dim3(NKVD / 32, HIDDEN / 32), 256, 0, stream>>>(Wv, Wvt, HIDDEN, NKVD);
  transpose_cast<<<dim3(NQ / 32, HIDDEN / 32), 256, 0, stream>>>(Wo, Wot, NQ, HIDDEN);

  gemm_qkv<<<dim3(NQKV / 128, MTOT / 128), 256, 0, stream>>>(xb, Wqt, Qb, Kb, Vtb);

  rope_kernel<<<(BATCH * SEQ * NHEADS * 64) / 256, 256, 0, stream>>>(Qb, NHEADS);
  rope_kernel<<<(BATCH * SEQ * NKV * 64) / 256, 256, 0, stream>>>(Kb, NKV);

  flash_attn<<<dim3(16, NHEADS, BATCH), 256, 0, stream>>>(Qb, Kb, Vtb, Ab);

  gemm_o<<<dim3(HIDDEN / 128, MTOT / 128), 256, 0, stream>>>(Ab, Wot, out, MTOT, HIDDEN, NQ);
}

// Round 6
// 340.913 us; speedup vs baseline: 1.5854x; 1.5854x over previous
//
#include <hip/hip_runtime.h>
#include <hip/hip_bf16.h>
#include <math.h>

#define HIDDEN 2048
#define NHEADS 16
#define NKV 4
#define HD 128
#define SEQ 2048
#define BATCH 2
#define MTOT (BATCH*SEQ)     // 4096
#define NQ (NHEADS*HD)       // 2048
#define NKVD (NKV*HD)        // 512
#define NQKV (NQ + 2*NKVD)   // 3072

typedef __attribute__((ext_vector_type(8))) short short8;
typedef __attribute__((ext_vector_type(4))) float float4v;

#if __has_builtin(__builtin_amdgcn_exp2f)
#define EXP2F __builtin_amdgcn_exp2f
#else
#define EXP2F exp2f
#endif
#define C1 0.1275174f   // (1/sqrt(128)) * log2(e)

static __device__ __forceinline__ unsigned short f2bf(float f) {
  union { float f; unsigned int u; } v; v.f = f;
  unsigned int r = v.u + 0x7FFF + ((v.u >> 16) & 1);
  return (unsigned short)(r >> 16);
}
static __device__ __forceinline__ float bf2f(unsigned short h) {
  union { unsigned int u; float f; } v; v.u = ((unsigned int)h) << 16;
  return v.f;
}

// async global->LDS, 16B per lane; LDS dest = uniform base + lane*16
static __device__ __forceinline__ void async16(const unsigned short* g, unsigned short* l) {
  __builtin_amdgcn_global_load_lds(
      (const __attribute__((address_space(1))) unsigned int*)g,
      (__attribute__((address_space(3))) unsigned int*)l, 16, 0, 0);
}

// ---------------- cast fp32 -> bf16 (vectorized x4) ----------------
__global__ void cast_f32_bf16(const float* __restrict__ in,
                              unsigned short* __restrict__ out, int n) {
  int i = (blockIdx.x * blockDim.x + threadIdx.x) * 4;
  if (i < n) {
    float4 v = *(const float4*)(in + i);
    ushort4 o;
    o.x = f2bf(v.x); o.y = f2bf(v.y); o.z = f2bf(v.z); o.w = f2bf(v.w);
    *(ushort4*)(out + i) = o;
  }
}

// ---------------- transpose + cast: W[K][N] fp32 -> Wt[N][K] bf16 ----------------
__global__ void transpose_cast(const float* __restrict__ W,
                               unsigned short* __restrict__ Wt, int K, int N) {
  __shared__ float tile[32][33];
  int tn = blockIdx.x * 32;
  int tk = blockIdx.y * 32;
  int tx = threadIdx.x & 31;
  int ty = threadIdx.x >> 5;  // 0..7
  #pragma unroll
  for (int i = 0; i < 4; i++) {
    int k = tk + ty + i * 8;
    tile[ty + i * 8][tx] = W[(size_t)k * N + tn + tx];
  }
  __syncthreads();
  #pragma unroll
  for (int i = 0; i < 4; i++) {
    int n = tn + ty + i * 8;
    Wt[(size_t)n * K + tk + tx] = f2bf(tile[tx][ty + i * 8]);
  }
}

// ---------------- RoPE in place on [B][S][nheads][128] bf16 ----------------
__global__ void rope_kernel(unsigned short* __restrict__ Qb, int nheads) {
  int idx = blockIdx.x * blockDim.x + threadIdx.x;
  int d = idx & 63;
  int hr = idx >> 6;                 // (b*SEQ + s)*nheads + h
  int spos = (hr / nheads) % SEQ;
  size_t base = (size_t)hr * HD;
  float inv = exp2f((float)d * -0.2076205059304601f);  // 10000^(-d/64)
  float ang = (float)spos * inv;
  float sn, cs;
  sincosf(ang, &sn, &cs);
  float q1 = bf2f(Qb[base + d]);
  float q2 = bf2f(Qb[base + d + 64]);
  Qb[base + d]      = f2bf(q1 * cs - q2 * sn);
  Qb[base + d + 64] = f2bf(q2 * cs + q1 * sn);
}

// ================= fused QKV GEMM: xb[4096][2048] x Wqkvt[3072][2048]^T ================
// dbuf LDS, swizzled staging/reads (2-way banks). V-blocks (bx>=20) use
// operand-swapped MFMA so V^T stores are row-coalesced.
__global__ __launch_bounds__(256) void gemm_qkv(
    const unsigned short* __restrict__ A,
    const unsigned short* __restrict__ Bt,
    unsigned short* __restrict__ Qb,
    unsigned short* __restrict__ Kb,
    unsigned short* __restrict__ Vt) {
  __shared__ unsigned short As0[128 * 32], Bs0[128 * 32];
  __shared__ unsigned short As1[128 * 32], Bs1[128 * 32];
  const int K = HIDDEN;
  int bm = blockIdx.y * 128, bn = blockIdx.x * 128;
  int tid = threadIdx.x, w = tid >> 6, lane = tid & 63;
  int wm = (w >> 1) * 64, wn = (w & 1) * 64;
  int m16 = lane & 15, quad = lane >> 4;
  int lrow = lane >> 2, lch = lane & 3;
  int lchs = lch ^ ((lrow >> 1) & 3);          // swizzled staging piece
  int qx = quad ^ ((m16 >> 1) & 3);            // swizzled read piece
  const unsigned short* Ag = A + (size_t)(bm + w * 32 + lrow) * K + lchs * 8;
  const unsigned short* Bg = Bt + (size_t)(bn + w * 32 + lrow) * K + lchs * 8;
  int woff = w * 1024;

  float4v acc[4][4];
  #pragma unroll
  for (int i = 0; i < 4; i++)
    #pragma unroll
    for (int j = 0; j < 4; j++) acc[i][j] = (float4v)0.0f;

  auto stage = [&](int k0, unsigned short* Asl, unsigned short* Bsl) {
    #pragma unroll
    for (int i = 0; i < 2; i++) {
      async16(Ag + (size_t)i * 16 * K + k0, Asl + woff + i * 512);
      async16(Bg + (size_t)i * 16 * K + k0, Bsl + woff + i * 512);
    }
  };
  auto computeN = [&](const unsigned short* As, const unsigned short* Bs) {
    short8 af[4], bfr[4];
    #pragma unroll
    for (int i = 0; i < 4; i++)
      af[i] = *(const short8*)(&As[(wm + i * 16 + m16) * 32 + qx * 8]);
    #pragma unroll
    for (int j = 0; j < 4; j++)
      bfr[j] = *(const short8*)(&Bs[(wn + j * 16 + m16) * 32 + qx * 8]);
    #pragma unroll
    for (int i = 0; i < 4; i++)
      #pragma unroll
      for (int j = 0; j < 4; j++)
        acc[i][j] = __builtin_amdgcn_mfma_f32_16x16x32_bf16(af[i], bfr[j], acc[i][j], 0, 0, 0);
  };
  auto computeS = [&](const unsigned short* As, const unsigned short* Bs) {
    short8 af[4], bfr[4];
    #pragma unroll
    for (int i = 0; i < 4; i++)
      af[i] = *(const short8*)(&As[(wm + i * 16 + m16) * 32 + qx * 8]);
    #pragma unroll
    for (int j = 0; j < 4; j++)
      bfr[j] = *(const short8*)(&Bs[(wn + j * 16 + m16) * 32 + qx * 8]);
    #pragma unroll
    for (int i = 0; i < 4; i++)
      #pragma unroll
      for (int j = 0; j < 4; j++)
        acc[i][j] = __builtin_amdgcn_mfma_f32_16x16x32_bf16(bfr[j], af[i], acc[i][j], 0, 0, 0);
  };

  bool isV = (blockIdx.x >= 20);
  stage(0, As0, Bs0);
  if (!isV) {
    for (int k0 = 0; k0 < K; k0 += 64) {
      __syncthreads();
      if (k0 + 32 < K) stage(k0 + 32, As1, Bs1);
      computeN(As0, Bs0);
      __syncthreads();
      if (k0 + 64 < K) stage(k0 + 64, As0, Bs0);
      computeN(As1, Bs1);
    }
  } else {
    for (int k0 = 0; k0 < K; k0 += 64) {
      __syncthreads();
      if (k0 + 32 < K) stage(k0 + 32, As1, Bs1);
      computeS(As0, Bs0);
      __syncthreads();
      if (k0 + 64 < K) stage(k0 + 64, As0, Bs0);
      computeS(As1, Bs1);
    }
  }

  if (blockIdx.x < 16) {
    #pragma unroll
    for (int i = 0; i < 4; i++)
      #pragma unroll
      for (int j = 0; j < 4; j++)
        #pragma unroll
        for (int r = 0; r < 4; r++) {
          int row = bm + wm + i * 16 + quad * 4 + r;
          int col = bn + wn + j * 16 + m16;
          Qb[(size_t)row * NQ + col] = f2bf(acc[i][j][r]);
        }
  } else if (!isV) {
    #pragma unroll
    for (int i = 0; i < 4; i++)
      #pragma unroll
      for (int j = 0; j < 4; j++)
        #pragma unroll
        for (int r = 0; r < 4; r++) {
          int row = bm + wm + i * 16 + quad * 4 + r;
          int col = bn - 2048 + wn + j * 16 + m16;
          Kb[(size_t)row * NKVD + col] = f2bf(acc[i][j][r]);
        }
  } else {
    // swapped layout: row(quad*4+r) = f-tile j, col(m16) = m-tile i
    #pragma unroll
    for (int i = 0; i < 4; i++)
      #pragma unroll
      for (int j = 0; j < 4; j++)
        #pragma unroll
        for (int r = 0; r < 4; r++) {
          int f = bn - 2560 + wn + j * 16 + quad * 4 + r;
          int m = bm + wm + i * 16 + m16;
          Vt[(size_t)f * MTOT + m] = f2bf(acc[i][j][r]);
        }
  }
}

// ================= O-projection GEMM (dbuf + swizzle, fp32 out) =================
__global__ __launch_bounds__(256) void gemm_o(
    const unsigned short* __restrict__ A,
    const unsigned short* __restrict__ Bt,
    float* __restrict__ C, int M, int N, int K) {
  __shared__ unsigned short As0[128 * 32], Bs0[128 * 32];
  __shared__ unsigned short As1[128 * 32], Bs1[128 * 32];
  int bm = blockIdx.y * 128, bn = blockIdx.x * 128;
  int tid = threadIdx.x, w = tid >> 6, lane = tid & 63;
  int wm = (w >> 1) * 64, wn = (w & 1) * 64;
  int m16 = lane & 15, quad = lane >> 4;
  int lrow = lane >> 2, lch = lane & 3;
  int lchs = lch ^ ((lrow >> 1) & 3);
  int qx = quad ^ ((m16 >> 1) & 3);
  const unsigned short* Ag = A + (size_t)(bm + w * 32 + lrow) * K + lchs * 8;
  const unsigned short* Bg = Bt + (size_t)(bn + w * 32 + lrow) * K + lchs * 8;
  int woff = w * 1024;

  float4v acc[4][4];
  #pragma unroll
  for (int i = 0; i < 4; i++)
    #pragma unroll
    for (int j = 0; j < 4; j++) acc[i][j] = (float4v)0.0f;

  auto stage = [&](int k0, unsigned short* Asl, unsigned short* Bsl) {
    #pragma unroll
    for (int i = 0; i < 2; i++) {
      async16(Ag + (size_t)i * 16 * K + k0, Asl + woff + i * 512);
      async16(Bg + (size_t)i * 16 * K + k0, Bsl + woff + i * 512);
    }
  };
  auto compute = [&](const unsigned short* As, const unsigned short* Bs) {
    short8 af[4], bfr[4];
    #pragma unroll
    for (int i = 0; i < 4; i++)
      af[i] = *(const short8*)(&As[(wm + i * 16 + m16) * 32 + qx * 8]);
    #pragma unroll
    for (int j = 0; j < 4; j++)
      bfr[j] = *(const short8*)(&Bs[(wn + j * 16 + m16) * 32 + qx * 8]);
    #pragma unroll
    for (int i = 0; i < 4; i++)
      #pragma unroll
      for (int j = 0; j < 4; j++)
        acc[i][j] = __builtin_amdgcn_mfma_f32_16x16x32_bf16(af[i], bfr[j], acc[i][j], 0, 0, 0);
  };

  stage(0, As0, Bs0);
  for (int k0 = 0; k0 < K; k0 += 64) {
    __syncthreads();
    if (k0 + 32 < K) stage(k0 + 32, As1, Bs1);
    compute(As0, Bs0);
    __syncthreads();
    if (k0 + 64 < K) stage(k0 + 64, As0, Bs0);
    compute(As1, Bs1);
  }

  #pragma unroll
  for (int i = 0; i < 4; i++)
    #pragma unroll
    for (int j = 0; j < 4; j++)
      #pragma unroll
      for (int r = 0; r < 4; r++) {
        int row = bm + wm + i * 16 + quad * 4 + r;
        int col = bn + wn + j * 16 + m16;
        C[(size_t)row * N + col] = acc[i][j][r];
      }
}

// ---------------- Flash attention: 48 KB LDS, P overlays dead K buffer ----------------
// Per iter: TOP barrier -> issue V(kt) -> S from CUR -> issue K(kt+1)->NXT ->
// softmax (P packed in regs) -> MID barrier (drains V+K; orders S-reads before
// P-writes) -> P-write into CUR (wave-private rows) -> PV -> loop.
// NOTE: do NOT force min-waves here — capping VGPRs below ~120 spills the
// accumulators to scratch (round-5 regression: 84 VGPR, 660 MB scratch traffic).
// At ~120 VGPR the HW allows 4 waves/SIMD; 48 KB LDS then gives 3 blocks/CU.
#define FLASH_TILE(CUR, NXT)                                                  \
  {                                                                           \
    const int ktb = kt * 64;                                                  \
    __syncthreads(); /* TOP */                                                \
    {                                                                         \
      const unsigned short* Vg = Vt + vgrow * (size_t)MTOT                    \
                                    + (size_t)b * SEQ + ktb + kcv * 32 + vlch * 8; \
      unsigned short* Vl = Vs + kcv * 4096 + ipv * 512;                       \
      _Pragma("unroll")                                                       \
      for (int i = 0; i < 4; i++) async16(Vg + (size_t)i * 16 * MTOT, Vl + i * 512); \
    }                                                                         \
    const bool act = (ktb <= wqmax);                                          \
    float4v sacc[2][4];                                                       \
    if (act) {                                                                \
      _Pragma("unroll") for (int qs = 0; qs < 2; qs++)                        \
        _Pragma("unroll") for (int s4 = 0; s4 < 4; s4++) sacc[qs][s4] = (float4v)0.0f; \
      _Pragma("unroll")                                                       \
      for (int s4 = 0; s4 < 4; s4++)                                          \
        _Pragma("unroll")                                                     \
        for (int c = 0; c < 4; c++) {                                         \
          short8 kf = *(const short8*)(&CUR[c * 2048 + (s4 * 16 + m16) * 32 + qx * 8]); \
          sacc[0][s4] = __builtin_amdgcn_mfma_f32_16x16x32_bf16(kf, qf[0][c], sacc[0][s4], 0, 0, 0); \
          sacc[1][s4] = __builtin_amdgcn_mfma_f32_16x16x32_bf16(kf, qf[1][c], sacc[1][s4], 0, 0, 0); \
        }                                                                     \
    }                                                                         \
    if (kt < H) {                                                             \
      const unsigned short* Kg = Kp + (((size_t)b * SEQ + (kt + 1) * 64 + lrow) * NKV + kvh) * HD + w * 32 + vlch * 8; \
      unsigned short* Kl = NXT + w * 2048;                                    \
      _Pragma("unroll")                                                       \
      for (int i = 0; i < 4; i++) async16(Kg + (size_t)i * 16 * NKV * HD, Kl + i * 512); \
    }                                                                         \
    unsigned int pu[2][4][2];                                                 \
    if (act) {                                                                \
      _Pragma("unroll")                                                       \
      for (int qs = 0; qs < 2; qs++) {                                        \
        const int qabs = wqbase + qs * 16 + m16;                              \
        const bool diag = (ktb + 63) > (wqbase + qs * 16);                    \
        float sv[4][4]; float mloc = -1e30f;                                  \
        if (diag) {                                                           \
          _Pragma("unroll") for (int s4 = 0; s4 < 4; s4++)                    \
            _Pragma("unroll") for (int r = 0; r < 4; r++) {                   \
              int kabs = ktb + s4 * 16 + quad * 4 + r;                        \
              float t = sacc[qs][s4][r];                                      \
              sv[s4][r] = (kabs > qabs) ? -1e30f : t;                         \
              mloc = fmaxf(mloc, sv[s4][r]); }                                \
        } else {                                                              \
          _Pragma("unroll") for (int s4 = 0; s4 < 4; s4++)                    \
            _Pragma("unroll") for (int r = 0; r < 4; r++) {                   \
              sv[s4][r] = sacc[qs][s4][r]; mloc = fmaxf(mloc, sv[s4][r]); }   \
        }                                                                     \
        mloc *= C1;                                                           \
        mloc = fmaxf(mloc, __shfl_xor(mloc, 16, 64));                         \
        mloc = fmaxf(mloc, __shfl_xor(mloc, 32, 64));                         \
        const float mnewS = fmaxf(miS[qs], mloc);                             \
        float rs = 0.0f;                                                      \
        _Pragma("unroll") for (int s4 = 0; s4 < 4; s4++) {                    \
          float p0 = EXP2F(__builtin_fmaf(sv[s4][0], C1, -mnewS));            \
          float p1 = EXP2F(__builtin_fmaf(sv[s4][1], C1, -mnewS));            \
          float p2 = EXP2F(__builtin_fmaf(sv[s4][2], C1, -mnewS));            \
          float p3 = EXP2F(__builtin_fmaf(sv[s4][3], C1, -mnewS));            \
          rs += p0 + p1 + p2 + p3;                                            \
          pu[qs][s4][0] = (__float_as_uint(p1) & 0xffff0000u) | (__float_as_uint(p0) >> 16); \
          pu[qs][s4][1] = (__float_as_uint(p3) & 0xffff0000u) | (__float_as_uint(p2) >> 16); \
        }                                                                     \
        rs += __shfl_xor(rs, 16, 64);                                         \
        rs += __shfl_xor(rs, 32, 64);                                         \
        const float alpha = EXP2F(miS[qs] - mnewS);                           \
        li[qs] = li[qs] * alpha + rs; miS[qs] = mnewS;                        \
        _Pragma("unroll") for (int ds = 0; ds < 8; ds++) oacc[ds][qs] *= alpha; \
      }                                                                       \
    }                                                                         \
    __syncthreads(); /* MID: drains V+K; all S-reads done before P overlay */ \
    if (act) {                                                                \
      unsigned int* Pp = (unsigned int*)CUR;                                  \
      _Pragma("unroll")                                                       \
      for (int qs = 0; qs < 2; qs++) {                                        \
        const int prow = qlocal0 + qs * 16 + m16;                             \
        const int psw = prow * 32; const int rx = prow & 7;                   \
        _Pragma("unroll") for (int s4 = 0; s4 < 4; s4++) {                    \
          uint2 u; u.x = pu[qs][s4][0]; u.y = pu[qs][s4][1];                  \
          int chunkW = s4 * 2 + (quad >> 1);                                  \
          *(uint2*)(&Pp[psw + ((chunkW ^ rx) << 2) + (quad & 1) * 2]) = u;    \
        }                                                                     \
      }                                                                       \
      const int r0 = qlocal0 + m16, r1 = qlocal0 + 16 + m16;                  \
      _Pragma("unroll")                                                       \
      for (int kc = 0; kc < 2; kc++) {                                        \
        short8 pf0 = *(const short8*)(&Pp[r0 * 32 + (((kc * 4 + quad) ^ (r0 & 7)) << 2)]); \
        short8 pf1 = *(const short8*)(&Pp[r1 * 32 + (((kc * 4 + quad) ^ (r1 & 7)) << 2)]); \
        _Pragma("unroll")                                                     \
        for (int ds = 0; ds < 8; ds++) {                                      \
          short8 vf = *(const short8*)(&Vs[kc * 4096 + (ds * 16 + m16) * 32 + qx * 8]); \
          oacc[ds][0] = __builtin_amdgcn_mfma_f32_16x16x32_bf16(vf, pf0, oacc[ds][0], 0, 0, 0); \
          oacc[ds][1] = __builtin_amdgcn_mfma_f32_16x16x32_bf16(vf, pf1, oacc[ds][1], 0, 0, 0); \
        }                                                                     \
      }                                                                       \
    }                                                                         \
  }

__global__ __launch_bounds__(256, 2) void flash_attn(
    const unsigned short* __restrict__ Q,
    const unsigned short* __restrict__ Kp,
    const unsigned short* __restrict__ Vt,
    unsigned short* __restrict__ O) {
  __shared__ unsigned short Ks0[4 * 64 * 32];  // 16 KB [dchunk][key][32d]; P overlay after S
  __shared__ unsigned short Ks1[4 * 64 * 32];  // 16 KB
  __shared__ unsigned short Vs[2 * 128 * 32];  // 16 KB [kchunk][d][32seq]

  int bx = blockIdx.x;            // 0..15
  int h  = blockIdx.y;
  int b  = blockIdx.z;
  int kvh = h >> 2;
  int H = 31 - bx, L = bx;
  int tid = threadIdx.x;
  int w = tid >> 6, lane = tid & 63;
  int m16 = lane & 15, quad = lane >> 4;
  int lrow = lane >> 2, lch = lane & 3;
  const int vlch = lch ^ ((lrow >> 1) & 3);   // swizzled staging piece
  const int qx = quad ^ ((m16 >> 1) & 3);     // swizzled read piece

  int wqbase = (w < 2) ? (H * 64 + w * 32) : (L * 64 + (w - 2) * 32);
  int wqmax = wqbase + 31;
  int qlocal0 = w * 32;
  const int kcv = w >> 1, ipv = (w & 1) * 4;
  const size_t vgrow = (size_t)kvh * HD + ipv * 16 + lrow;

  short8 qf[2][4];
  #pragma unroll
  for (int qs = 0; qs < 2; qs++) {
    size_t qbase = (((size_t)b * SEQ + wqbase + qs * 16 + m16) * NHEADS + h) * HD;
    #pragma unroll
    for (int c = 0; c < 4; c++)
      qf[qs][c] = *(const short8*)(Q + qbase + c * 32 + quad * 8);
  }

  float4v oacc[8][2];
  #pragma unroll
  for (int ds = 0; ds < 8; ds++) { oacc[ds][0] = (float4v)0.0f; oacc[ds][1] = (float4v)0.0f; }
  float miS[2] = {-1e30f, -1e30f}, li[2] = {0.0f, 0.0f};

  // prologue: stage K(0) into Ks0 (drained at first TOP barrier)
  {
    const unsigned short* Kg = Kp + (((size_t)b * SEQ + lrow) * NKV + kvh) * HD + w * 32 + vlch * 8;
    unsigned short* Kl = Ks0 + w * 2048;
    #pragma unroll
    for (int i = 0; i < 4; i++) async16(Kg + (size_t)i * 16 * NKV * HD, Kl + i * 512);
  }

  int kt = 0;
  for (;;) {
    FLASH_TILE(Ks0, Ks1)
    if (++kt > H) break;
    FLASH_TILE(Ks1, Ks0)
    if (++kt > H) break;
  }

  #pragma unroll
  for (int qs = 0; qs < 2; qs++) {
    float inv = 1.0f / li[qs];
    int qabs = wqbase + qs * 16 + m16;
    size_t obase = (((size_t)b * SEQ + qabs) * NHEADS + h) * HD + quad * 4;
    #pragma unroll
    for (int ds = 0; ds < 8; ds++) {
      float v0 = oacc[ds][qs][0] * inv;
      float v1 = oacc[ds][qs][1] * inv;
      float v2 = oacc[ds][qs][2] * inv;
      float v3 = oacc[ds][qs][3] * inv;
      uint2 u;
      u.x = ((unsigned)f2bf(v1) << 16) | f2bf(v0);
      u.y = ((unsigned)f2bf(v3) << 16) | f2bf(v2);
      *(uint2*)(O + obase + ds * 16) = u;
    }
  }
}

extern "C" void kernel_launch(void* const* d_in, const int* in_sizes, int n_in,
                              void* d_out, int out_size, void* d_ws, size_t ws_size,
                              hipStream_t stream) {
  const float* x  = (const float*)d_in[0];
  const float* Wq = (const float*)d_in[1];
  const float* Wk = (const float*)d_in[2];
  const float* Wv = (const float*)d_in[3];
  const float* Wo = (const float*)d_in[4];
  float* out = (float*)d_out;

  unsigned short* ws = (unsigned short*)d_ws;
  unsigned short* xb  = ws;                              // [4096][2048]
  unsigned short* Wqt = xb  + (size_t)MTOT * HIDDEN;     // [2048][2048] (Wqt/Wkt/Wvt contiguous = Wqkvt)
  unsigned short* Wkt = Wqt + (size_t)NQ * HIDDEN;       // [512][2048]
  unsigned short* Wvt = Wkt + (size_t)NKVD * HIDDEN;     // [512][2048]
  unsigned short* Wot = Wvt + (size_t)NKVD * HIDDEN;     // [2048][2048]
  unsigned short* Qb  = Wot + (size_t)NQ * HIDDEN;       // [4096][2048]
  unsigned short* Kb  = Qb  + (size_t)MTOT * NQ;         // [4096][512]
  unsigned short* Vtb = Kb  + (size_t)MTOT * NKVD;       // [512][4096]  (V^T)
  unsigned short* Ab  = Vtb + (size_t)MTOT * NKVD;       // [4096][2048]

  cast_f32_bf16<<<(MTOT * HIDDEN / 4 + 255) / 256, 256, 0, stream>>>(x, xb, MTOT * HIDDEN);
  transpose_cast<<<dim3(NQ / 32, HIDDEN / 32), 256, 0, stream>>>(Wq, Wqt, HIDDEN, NQ);
  transpose_cast<<<dim3(NKVD / 32, HIDDEN / 32), 256, 0, stream>>>(Wk, Wkt, HIDDEN, NKVD);
  transpose_cast<<<dim3(NKVD / 32, HIDDEN / 32), 256, 0, stream>>>(Wv, Wvt, HIDDEN, NKVD);
  transpose_cast<<<dim3(NQ / 32, HIDDEN / 32), 256, 0, stream>>>(Wo, Wot, NQ, HIDDEN);

  gemm_qkv<<<dim3(NQKV / 128, MTOT / 128), 256, 0, stream>>>(xb, Wqt, Qb, Kb, Vtb);

  rope_kernel<<<(BATCH * SEQ * NHEADS * 64) / 256, 256, 0, stream>>>(Qb, NHEADS);
  rope_kernel<<<(BATCH * SEQ * NKV * 64) / 256, 256, 0, stream>>>(Kb, NKV);

  flash_attn<<<dim3(16, NHEADS, BATCH), 256, 0, stream>>>(Qb, Kb, Vtb, Ab);

  gemm_o<<<dim3(HIDDEN / 128, MTOT / 128), 256, 0, stream>>>(Ab, Wot, out, MTOT, HIDDEN, NQ);
}

// Round 7
// 311.583 us; speedup vs baseline: 1.7347x; 1.0941x over previous
//
#include <hip/hip_runtime.h>
#include <hip/hip_bf16.h>
#include <math.h>

#define HIDDEN 2048
#define NHEADS 16
#define NKV 4
#define HD 128
#define SEQ 2048
#define BATCH 2
#define MTOT (BATCH*SEQ)     // 4096
#define NQ (NHEADS*HD)       // 2048
#define NKVD (NKV*HD)        // 512
#define NQKV (NQ + 2*NKVD)   // 3072

typedef __attribute__((ext_vector_type(8))) short short8;
typedef __attribute__((ext_vector_type(4))) float float4v;

#if __has_builtin(__builtin_amdgcn_exp2f)
#define EXP2F __builtin_amdgcn_exp2f
#else
#define EXP2F exp2f
#endif
#define C1 0.1275174f   // (1/sqrt(128)) * log2(e)

static __device__ __forceinline__ unsigned short f2bf(float f) {
  union { float f; unsigned int u; } v; v.f = f;
  unsigned int r = v.u + 0x7FFF + ((v.u >> 16) & 1);
  return (unsigned short)(r >> 16);
}
static __device__ __forceinline__ float bf2f(unsigned short h) {
  union { unsigned int u; float f; } v; v.u = ((unsigned int)h) << 16;
  return v.f;
}

// async global->LDS, 16B per lane; LDS dest = uniform base + lane*16
static __device__ __forceinline__ void async16(const unsigned short* g, unsigned short* l) {
  __builtin_amdgcn_global_load_lds(
      (const __attribute__((address_space(1))) unsigned int*)g,
      (__attribute__((address_space(3))) unsigned int*)l, 16, 0, 0);
}

// ---------------- cast fp32 -> bf16 (vectorized x4) ----------------
__global__ void cast_f32_bf16(const float* __restrict__ in,
                              unsigned short* __restrict__ out, int n) {
  int i = (blockIdx.x * blockDim.x + threadIdx.x) * 4;
  if (i < n) {
    float4 v = *(const float4*)(in + i);
    ushort4 o;
    o.x = f2bf(v.x); o.y = f2bf(v.y); o.z = f2bf(v.z); o.w = f2bf(v.w);
    *(ushort4*)(out + i) = o;
  }
}

// ---------------- transpose + cast: W[K][N] fp32 -> Wt[N][K] bf16 ----------------
__global__ void transpose_cast(const float* __restrict__ W,
                               unsigned short* __restrict__ Wt, int K, int N) {
  __shared__ float tile[32][33];
  int tn = blockIdx.x * 32;
  int tk = blockIdx.y * 32;
  int tx = threadIdx.x & 31;
  int ty = threadIdx.x >> 5;  // 0..7
  #pragma unroll
  for (int i = 0; i < 4; i++) {
    int k = tk + ty + i * 8;
    tile[ty + i * 8][tx] = W[(size_t)k * N + tn + tx];
  }
  __syncthreads();
  #pragma unroll
  for (int i = 0; i < 4; i++) {
    int n = tn + ty + i * 8;
    Wt[(size_t)n * K + tk + tx] = f2bf(tile[tx][ty + i * 8]);
  }
}

// ---------------- RoPE in place on [B][S][nheads][128] bf16 ----------------
__global__ void rope_kernel(unsigned short* __restrict__ Qb, int nheads) {
  int idx = blockIdx.x * blockDim.x + threadIdx.x;
  int d = idx & 63;
  int hr = idx >> 6;                 // (b*SEQ + s)*nheads + h
  int spos = (hr / nheads) % SEQ;
  size_t base = (size_t)hr * HD;
  float inv = exp2f((float)d * -0.2076205059304601f);  // 10000^(-d/64)
  float ang = (float)spos * inv;
  float sn, cs;
  sincosf(ang, &sn, &cs);
  float q1 = bf2f(Qb[base + d]);
  float q2 = bf2f(Qb[base + d + 64]);
  Qb[base + d]      = f2bf(q1 * cs - q2 * sn);
  Qb[base + d + 64] = f2bf(q2 * cs + q1 * sn);
}

// ================= fused QKV GEMM: xb[4096][2048] x Wqkvt[3072][2048]^T ================
// dbuf LDS, swizzled staging/reads (2-way banks). V-blocks (bx>=20) use
// operand-swapped MFMA so V^T stores are row-coalesced.
__global__ __launch_bounds__(256) void gemm_qkv(
    const unsigned short* __restrict__ A,
    const unsigned short* __restrict__ Bt,
    unsigned short* __restrict__ Qb,
    unsigned short* __restrict__ Kb,
    unsigned short* __restrict__ Vt) {
  __shared__ unsigned short As0[128 * 32], Bs0[128 * 32];
  __shared__ unsigned short As1[128 * 32], Bs1[128 * 32];
  const int K = HIDDEN;
  int bm = blockIdx.y * 128, bn = blockIdx.x * 128;
  int tid = threadIdx.x, w = tid >> 6, lane = tid & 63;
  int wm = (w >> 1) * 64, wn = (w & 1) * 64;
  int m16 = lane & 15, quad = lane >> 4;
  int lrow = lane >> 2, lch = lane & 3;
  int lchs = lch ^ ((lrow >> 1) & 3);          // swizzled staging piece
  int qx = quad ^ ((m16 >> 1) & 3);            // swizzled read piece
  const unsigned short* Ag = A + (size_t)(bm + w * 32 + lrow) * K + lchs * 8;
  const unsigned short* Bg = Bt + (size_t)(bn + w * 32 + lrow) * K + lchs * 8;
  int woff = w * 1024;

  float4v acc[4][4];
  #pragma unroll
  for (int i = 0; i < 4; i++)
    #pragma unroll
    for (int j = 0; j < 4; j++) acc[i][j] = (float4v)0.0f;

  auto stage = [&](int k0, unsigned short* Asl, unsigned short* Bsl) {
    #pragma unroll
    for (int i = 0; i < 2; i++) {
      async16(Ag + (size_t)i * 16 * K + k0, Asl + woff + i * 512);
      async16(Bg + (size_t)i * 16 * K + k0, Bsl + woff + i * 512);
    }
  };
  auto computeN = [&](const unsigned short* As, const unsigned short* Bs) {
    short8 af[4], bfr[4];
    #pragma unroll
    for (int i = 0; i < 4; i++)
      af[i] = *(const short8*)(&As[(wm + i * 16 + m16) * 32 + qx * 8]);
    #pragma unroll
    for (int j = 0; j < 4; j++)
      bfr[j] = *(const short8*)(&Bs[(wn + j * 16 + m16) * 32 + qx * 8]);
    #pragma unroll
    for (int i = 0; i < 4; i++)
      #pragma unroll
      for (int j = 0; j < 4; j++)
        acc[i][j] = __builtin_amdgcn_mfma_f32_16x16x32_bf16(af[i], bfr[j], acc[i][j], 0, 0, 0);
  };
  auto computeS = [&](const unsigned short* As, const unsigned short* Bs) {
    short8 af[4], bfr[4];
    #pragma unroll
    for (int i = 0; i < 4; i++)
      af[i] = *(const short8*)(&As[(wm + i * 16 + m16) * 32 + qx * 8]);
    #pragma unroll
    for (int j = 0; j < 4; j++)
      bfr[j] = *(const short8*)(&Bs[(wn + j * 16 + m16) * 32 + qx * 8]);
    #pragma unroll
    for (int i = 0; i < 4; i++)
      #pragma unroll
      for (int j = 0; j < 4; j++)
        acc[i][j] = __builtin_amdgcn_mfma_f32_16x16x32_bf16(bfr[j], af[i], acc[i][j], 0, 0, 0);
  };

  bool isV = (blockIdx.x >= 20);
  stage(0, As0, Bs0);
  if (!isV) {
    for (int k0 = 0; k0 < K; k0 += 64) {
      __syncthreads();
      if (k0 + 32 < K) stage(k0 + 32, As1, Bs1);
      computeN(As0, Bs0);
      __syncthreads();
      if (k0 + 64 < K) stage(k0 + 64, As0, Bs0);
      computeN(As1, Bs1);
    }
  } else {
    for (int k0 = 0; k0 < K; k0 += 64) {
      __syncthreads();
      if (k0 + 32 < K) stage(k0 + 32, As1, Bs1);
      computeS(As0, Bs0);
      __syncthreads();
      if (k0 + 64 < K) stage(k0 + 64, As0, Bs0);
      computeS(As1, Bs1);
    }
  }

  if (blockIdx.x < 16) {
    #pragma unroll
    for (int i = 0; i < 4; i++)
      #pragma unroll
      for (int j = 0; j < 4; j++)
        #pragma unroll
        for (int r = 0; r < 4; r++) {
          int row = bm + wm + i * 16 + quad * 4 + r;
          int col = bn + wn + j * 16 + m16;
          Qb[(size_t)row * NQ + col] = f2bf(acc[i][j][r]);
        }
  } else if (!isV) {
    #pragma unroll
    for (int i = 0; i < 4; i++)
      #pragma unroll
      for (int j = 0; j < 4; j++)
        #pragma unroll
        for (int r = 0; r < 4; r++) {
          int row = bm + wm + i * 16 + quad * 4 + r;
          int col = bn - 2048 + wn + j * 16 + m16;
          Kb[(size_t)row * NKVD + col] = f2bf(acc[i][j][r]);
        }
  } else {
    // swapped layout: row(quad*4+r) = f-tile j, col(m16) = m-tile i
    #pragma unroll
    for (int i = 0; i < 4; i++)
      #pragma unroll
      for (int j = 0; j < 4; j++)
        #pragma unroll
        for (int r = 0; r < 4; r++) {
          int f = bn - 2560 + wn + j * 16 + quad * 4 + r;
          int m = bm + wm + i * 16 + m16;
          Vt[(size_t)f * MTOT + m] = f2bf(acc[i][j][r]);
        }
  }
}

// ================= O-projection GEMM (dbuf + swizzle, fp32 out) =================
__global__ __launch_bounds__(256) void gemm_o(
    const unsigned short* __restrict__ A,
    const unsigned short* __restrict__ Bt,
    float* __restrict__ C, int M, int N, int K) {
  __shared__ unsigned short As0[128 * 32], Bs0[128 * 32];
  __shared__ unsigned short As1[128 * 32], Bs1[128 * 32];
  int bm = blockIdx.y * 128, bn = blockIdx.x * 128;
  int tid = threadIdx.x, w = tid >> 6, lane = tid & 63;
  int wm = (w >> 1) * 64, wn = (w & 1) * 64;
  int m16 = lane & 15, quad = lane >> 4;
  int lrow = lane >> 2, lch = lane & 3;
  int lchs = lch ^ ((lrow >> 1) & 3);
  int qx = quad ^ ((m16 >> 1) & 3);
  const unsigned short* Ag = A + (size_t)(bm + w * 32 + lrow) * K + lchs * 8;
  const unsigned short* Bg = Bt + (size_t)(bn + w * 32 + lrow) * K + lchs * 8;
  int woff = w * 1024;

  float4v acc[4][4];
  #pragma unroll
  for (int i = 0; i < 4; i++)
    #pragma unroll
    for (int j = 0; j < 4; j++) acc[i][j] = (float4v)0.0f;

  auto stage = [&](int k0, unsigned short* Asl, unsigned short* Bsl) {
    #pragma unroll
    for (int i = 0; i < 2; i++) {
      async16(Ag + (size_t)i * 16 * K + k0, Asl + woff + i * 512);
      async16(Bg + (size_t)i * 16 * K + k0, Bsl + woff + i * 512);
    }
  };
  auto compute = [&](const unsigned short* As, const unsigned short* Bs) {
    short8 af[4], bfr[4];
    #pragma unroll
    for (int i = 0; i < 4; i++)
      af[i] = *(const short8*)(&As[(wm + i * 16 + m16) * 32 + qx * 8]);
    #pragma unroll
    for (int j = 0; j < 4; j++)
      bfr[j] = *(const short8*)(&Bs[(wn + j * 16 + m16) * 32 + qx * 8]);
    #pragma unroll
    for (int i = 0; i < 4; i++)
      #pragma unroll
      for (int j = 0; j < 4; j++)
        acc[i][j] = __builtin_amdgcn_mfma_f32_16x16x32_bf16(af[i], bfr[j], acc[i][j], 0, 0, 0);
  };

  stage(0, As0, Bs0);
  for (int k0 = 0; k0 < K; k0 += 64) {
    __syncthreads();
    if (k0 + 32 < K) stage(k0 + 32, As1, Bs1);
    compute(As0, Bs0);
    __syncthreads();
    if (k0 + 64 < K) stage(k0 + 64, As0, Bs0);
    compute(As1, Bs1);
  }

  #pragma unroll
  for (int i = 0; i < 4; i++)
    #pragma unroll
    for (int j = 0; j < 4; j++)
      #pragma unroll
      for (int r = 0; r < 4; r++) {
        int row = bm + wm + i * 16 + quad * 4 + r;
        int col = bn + wn + j * 16 + m16;
        C[(size_t)row * N + col] = acc[i][j][r];
      }
}

// ---------------- Flash attention: vertical H/L split, dedicated Ps ----------------
// Every wave handles 16 H-rows (qs=0, always active) + 16 L-rows (qs=1, active
// while ktb <= lmax_w) -> MFMA load is uniform across all 4 SIMDs (round-6 fix:
// tile-per-wave-pair left SIMDs 2-3 idle ~65% of iterations).
// Pipeline: TOP barrier -> issue V(kt)+K(kt+1) -> S-MFMA -> softmax + P-write
// (pre-MID, dedicated Ps) -> MID barrier (drains V+K under S+softmax) -> PV.
// NOTE: no min-waves clamp — capping VGPR below ~120 spills oacc (round-5: 660 MB
// scratch traffic). Grid (512 blocks) limits us to 2 blocks/CU anyway -> 64 KB LDS ok.
#define FLASH_TILE(CUR, NXT)                                                  \
  {                                                                           \
    const int ktb = kt * 64;                                                  \
    __syncthreads(); /* TOP: all prior-iter LDS reads done, NXT dead */       \
    {                                                                         \
      const unsigned short* Vg = Vt + vgrow * (size_t)MTOT                    \
                                    + (size_t)b * SEQ + ktb + kcv * 32 + vlch * 8; \
      unsigned short* Vl = Vs + kcv * 4096 + ipv * 512;                       \
      _Pragma("unroll")                                                       \
      for (int i = 0; i < 4; i++) async16(Vg + (size_t)i * 16 * MTOT, Vl + i * 512); \
    }                                                                         \
    if (kt < H) {                                                             \
      const unsigned short* Kg = Kp + (((size_t)b * SEQ + (kt + 1) * 64 + lrow) * NKV + kvh) * HD + w * 32 + vlch * 8; \
      unsigned short* Kl = NXT + w * 2048;                                    \
      _Pragma("unroll")                                                       \
      for (int i = 0; i < 4; i++) async16(Kg + (size_t)i * 16 * NKV * HD, Kl + i * 512); \
    }                                                                         \
    const bool act1 = (ktb <= lmax_w);                                        \
    float4v sacc[2][4];                                                       \
    _Pragma("unroll") for (int s4 = 0; s4 < 4; s4++) {                        \
      sacc[0][s4] = (float4v)0.0f; sacc[1][s4] = (float4v)0.0f; }             \
    if (act1) {                                                               \
      _Pragma("unroll")                                                       \
      for (int s4 = 0; s4 < 4; s4++)                                          \
        _Pragma("unroll")                                                     \
        for (int c = 0; c < 4; c++) {                                         \
          short8 kf = *(const short8*)(&CUR[c * 2048 + (s4 * 16 + m16) * 32 + qx * 8]); \
          sacc[0][s4] = __builtin_amdgcn_mfma_f32_16x16x32_bf16(kf, qf[0][c], sacc[0][s4], 0, 0, 0); \
          sacc[1][s4] = __builtin_amdgcn_mfma_f32_16x16x32_bf16(kf, qf[1][c], sacc[1][s4], 0, 0, 0); \
        }                                                                     \
    } else {                                                                  \
      _Pragma("unroll")                                                       \
      for (int s4 = 0; s4 < 4; s4++)                                          \
        _Pragma("unroll")                                                     \
        for (int c = 0; c < 4; c++) {                                         \
          short8 kf = *(const short8*)(&CUR[c * 2048 + (s4 * 16 + m16) * 32 + qx * 8]); \
          sacc[0][s4] = __builtin_amdgcn_mfma_f32_16x16x32_bf16(kf, qf[0][c], sacc[0][s4], 0, 0, 0); \
        }                                                                     \
    }                                                                         \
    _Pragma("unroll")                                                         \
    for (int qs = 0; qs < 2; qs++) {                                          \
      if (qs == 0 || act1) {                                                  \
        const int tb = qs ? L : H;                                            \
        const int qabs = tb * 64 + w * 16 + m16;                              \
        const bool diag = (kt == tb);                                         \
        float sv[4][4]; float mloc = -1e30f;                                  \
        if (diag) {                                                           \
          _Pragma("unroll") for (int s4 = 0; s4 < 4; s4++)                    \
            _Pragma("unroll") for (int r = 0; r < 4; r++) {                   \
              int kabs = ktb + s4 * 16 + quad * 4 + r;                        \
              float t = sacc[qs][s4][r];                                      \
              sv[s4][r] = (kabs > qabs) ? -1e30f : t;                         \
              mloc = fmaxf(mloc, sv[s4][r]); }                                \
        } else {                                                              \
          _Pragma("unroll") for (int s4 = 0; s4 < 4; s4++)                    \
            _Pragma("unroll") for (int r = 0; r < 4; r++) {                   \
              sv[s4][r] = sacc[qs][s4][r]; mloc = fmaxf(mloc, sv[s4][r]); }   \
        }                                                                     \
        mloc *= C1;                                                           \
        mloc = fmaxf(mloc, __shfl_xor(mloc, 16, 64));                         \
        mloc = fmaxf(mloc, __shfl_xor(mloc, 32, 64));                         \
        const float mnewS = fmaxf(miS[qs], mloc);                             \
        const int prow = qs * 64 + w * 16 + m16;                              \
        const int psw = prow * 32; const int rx = prow & 7;                   \
        float rs = 0.0f;                                                      \
        _Pragma("unroll") for (int s4 = 0; s4 < 4; s4++) {                    \
          float p0 = EXP2F(__builtin_fmaf(sv[s4][0], C1, -mnewS));            \
          float p1 = EXP2F(__builtin_fmaf(sv[s4][1], C1, -mnewS));            \
          float p2 = EXP2F(__builtin_fmaf(sv[s4][2], C1, -mnewS));            \
          float p3 = EXP2F(__builtin_fmaf(sv[s4][3], C1, -mnewS));            \
          rs += p0 + p1 + p2 + p3;                                            \
          uint2 u;                                                            \
          u.x = (__float_as_uint(p1) & 0xffff0000u) | (__float_as_uint(p0) >> 16); \
          u.y = (__float_as_uint(p3) & 0xffff0000u) | (__float_as_uint(p2) >> 16); \
          int chunkW = s4 * 2 + (quad >> 1);                                  \
          *(uint2*)(&Ps[psw + ((chunkW ^ rx) << 2) + (quad & 1) * 2]) = u;    \
        }                                                                     \
        rs += __shfl_xor(rs, 16, 64);                                         \
        rs += __shfl_xor(rs, 32, 64);                                         \
        const float alpha = EXP2F(miS[qs] - mnewS);                           \
        li[qs] = li[qs] * alpha + rs; miS[qs] = mnewS;                        \
        _Pragma("unroll") for (int ds = 0; ds < 8; ds++) oacc[ds][qs] *= alpha; \
      }                                                                       \
    }                                                                         \
    __syncthreads(); /* MID: drains V(kt)+K(kt+1), covered by S+softmax */    \
    {                                                                         \
      const int r0 = w * 16 + m16, r1 = 64 + w * 16 + m16;                    \
      if (act1) {                                                             \
        _Pragma("unroll")                                                     \
        for (int kc = 0; kc < 2; kc++) {                                      \
          short8 pf0 = *(const short8*)(&Ps[r0 * 32 + (((kc * 4 + quad) ^ (r0 & 7)) << 2)]); \
          short8 pf1 = *(const short8*)(&Ps[r1 * 32 + (((kc * 4 + quad) ^ (r1 & 7)) << 2)]); \
          _Pragma("unroll")                                                   \
          for (int ds = 0; ds < 8; ds++) {                                    \
            short8 vf = *(const short8*)(&Vs[kc * 4096 + (ds * 16 + m16) * 32 + qx * 8]); \
            oacc[ds][0] = __builtin_amdgcn_mfma_f32_16x16x32_bf16(vf, pf0, oacc[ds][0], 0, 0, 0); \
            oacc[ds][1] = __builtin_amdgcn_mfma_f32_16x16x32_bf16(vf, pf1, oacc[ds][1], 0, 0, 0); \
          }                                                                   \
        }                                                                     \
      } else {                                                                \
        _Pragma("unroll")                                                     \
        for (int kc = 0; kc < 2; kc++) {                                      \
          short8 pf0 = *(const short8*)(&Ps[r0 * 32 + (((kc * 4 + quad) ^ (r0 & 7)) << 2)]); \
          _Pragma("unroll")                                                   \
          for (int ds = 0; ds < 8; ds++) {                                    \
            short8 vf = *(const short8*)(&Vs[kc * 4096 + (ds * 16 + m16) * 32 + qx * 8]); \
            oacc[ds][0] = __builtin_amdgcn_mfma_f32_16x16x32_bf16(vf, pf0, oacc[ds][0], 0, 0, 0); \
          }                                                                   \
        }                                                                     \
      }                                                                       \
    }                                                                         \
  }

__global__ __launch_bounds__(256, 2) void flash_attn(
    const unsigned short* __restrict__ Q,
    const unsigned short* __restrict__ Kp,
    const unsigned short* __restrict__ Vt,
    unsigned short* __restrict__ O) {
  __shared__ unsigned short Ks0[4 * 64 * 32];  // 16 KB [dchunk][key][32d]
  __shared__ unsigned short Ks1[4 * 64 * 32];  // 16 KB
  __shared__ unsigned short Vs[2 * 128 * 32];  // 16 KB [kchunk][d][32seq]
  __shared__ unsigned int   Ps[128 * 32];      // 16 KB swizzled P[q][k/2]

  int bx = blockIdx.x;            // 0..15
  int h  = blockIdx.y;
  int b  = blockIdx.z;
  int kvh = h >> 2;
  int H = 31 - bx, L = bx;
  int tid = threadIdx.x;
  int w = tid >> 6, lane = tid & 63;
  int m16 = lane & 15, quad = lane >> 4;
  int lrow = lane >> 2, lch = lane & 3;
  const int vlch = lch ^ ((lrow >> 1) & 3);   // swizzled staging piece
  const int qx = quad ^ ((m16 >> 1) & 3);     // swizzled read piece
  const int lmax_w = L * 64 + w * 16 + 15;    // qs=1 active while ktb <= lmax_w

  int qlocal0 = w * 16;
  const int kcv = w >> 1, ipv = (w & 1) * 4;
  const size_t vgrow = (size_t)kvh * HD + ipv * 16 + lrow;
  (void)qlocal0;

  // qs=0 -> H-tile rows [H*64 + w*16, +16); qs=1 -> L-tile rows [L*64 + w*16, +16)
  short8 qf[2][4];
  #pragma unroll
  for (int qs = 0; qs < 2; qs++) {
    int tb = qs ? L : H;
    size_t qbase = (((size_t)b * SEQ + tb * 64 + w * 16 + m16) * NHEADS + h) * HD;
    #pragma unroll
    for (int c = 0; c < 4; c++)
      qf[qs][c] = *(const short8*)(Q + qbase + c * 32 + quad * 8);
  }

  float4v oacc[8][2];
  #pragma unroll
  for (int ds = 0; ds < 8; ds++) { oacc[ds][0] = (float4v)0.0f; oacc[ds][1] = (float4v)0.0f; }
  float miS[2] = {-1e30f, -1e30f}, li[2] = {0.0f, 0.0f};

  // prologue: stage K(0) into Ks0 (drained at first TOP barrier)
  {
    const unsigned short* Kg = Kp + (((size_t)b * SEQ + lrow) * NKV + kvh) * HD + w * 32 + vlch * 8;
    unsigned short* Kl = Ks0 + w * 2048;
    #pragma unroll
    for (int i = 0; i < 4; i++) async16(Kg + (size_t)i * 16 * NKV * HD, Kl + i * 512);
  }

  int kt = 0;
  for (;;) {
    FLASH_TILE(Ks0, Ks1)
    if (++kt > H) break;
    FLASH_TILE(Ks1, Ks0)
    if (++kt > H) break;
  }

  #pragma unroll
  for (int qs = 0; qs < 2; qs++) {
    float inv = 1.0f / li[qs];
    int tb = qs ? L : H;
    int qabs = tb * 64 + w * 16 + m16;
    size_t obase = (((size_t)b * SEQ + qabs) * NHEADS + h) * HD + quad * 4;
    #pragma unroll
    for (int ds = 0; ds < 8; ds++) {
      float v0 = oacc[ds][qs][0] * inv;
      float v1 = oacc[ds][qs][1] * inv;
      float v2 = oacc[ds][qs][2] * inv;
      float v3 = oacc[ds][qs][3] * inv;
      uint2 u;
      u.x = ((unsigned)f2bf(v1) << 16) | f2bf(v0);
      u.y = ((unsigned)f2bf(v3) << 16) | f2bf(v2);
      *(uint2*)(O + obase + ds * 16) = u;
    }
  }
}

extern "C" void kernel_launch(void* const* d_in, const int* in_sizes, int n_in,
                              void* d_out, int out_size, void* d_ws, size_t ws_size,
                              hipStream_t stream) {
  const float* x  = (const float*)d_in[0];
  const float* Wq = (const float*)d_in[1];
  const float* Wk = (const float*)d_in[2];
  const float* Wv = (const float*)d_in[3];
  const float* Wo = (const float*)d_in[4];
  float* out = (float*)d_out;

  unsigned short* ws = (unsigned short*)d_ws;
  unsigned short* xb  = ws;                              // [4096][2048]
  unsigned short* Wqt = xb  + (size_t)MTOT * HIDDEN;     // [2048][2048] (Wqt/Wkt/Wvt contiguous = Wqkvt)
  unsigned short* Wkt = Wqt + (size_t)NQ * HIDDEN;       // [512][2048]
  unsigned short* Wvt = Wkt + (size_t)NKVD * HIDDEN;     // [512][2048]
  unsigned short* Wot = Wvt + (size_t)NKVD * HIDDEN;     // [2048][2048]
  unsigned short* Qb  = Wot + (size_t)NQ * HIDDEN;       // [4096][2048]
  unsigned short* Kb  = Qb  + (size_t)MTOT * NQ;         // [4096][512]
  unsigned short* Vtb = Kb  + (size_t)MTOT * NKVD;       // [512][4096]  (V^T)
  unsigned short* Ab  = Vtb + (size_t)MTOT * NKVD;       // [4096][2048]

  cast_f32_bf16<<<(MTOT * HIDDEN / 4 + 255) / 256, 256, 0, stream>>>(x, xb, MTOT * HIDDEN);
  transpose_cast<<<dim3(NQ / 32, HIDDEN / 32), 256, 0, stream>>>(Wq, Wqt, HIDDEN, NQ);
  transpose_cast<<<dim3(NKVD / 32, HIDDEN / 32), 256, 0, stream>>>(Wk, Wkt, HIDDEN, NKVD);
  transpose_cast<<<dim3(NKVD / 32, HIDDEN / 32), 256, 0, stream>>>(Wv, Wvt, HIDDEN, NKVD);
  transpose_cast<<<dim3(NQ / 32, HIDDEN / 32), 256, 0, stream>>>(Wo, Wot, NQ, HIDDEN);

  gemm_qkv<<<dim3(NQKV / 128, MTOT / 128), 256, 0, stream>>>(xb, Wqt, Qb, Kb, Vtb);

  rope_kernel<<<(BATCH * SEQ * NHEADS * 64) / 256, 256, 0, stream>>>(Qb, NHEADS);
  rope_kernel<<<(BATCH * SEQ * NKV * 64) / 256, 256, 0, stream>>>(Kb, NKV);

  flash_attn<<<dim3(16, NHEADS, BATCH), 256, 0, stream>>>(Qb, Kb, Vtb, Ab);

  gemm_o<<<dim3(HIDDEN / 128, MTOT / 128), 256, 0, stream>>>(Ab, Wot, out, MTOT, HIDDEN, NQ);
}